// Round 11
// baseline (193.568 us; speedup 1.0000x reference)
//
#include <hip/hip_runtime.h>
#include <hip/hip_bf16.h>
#include <math.h>

// Problem constants (reference: B=32, P=256, D=64, T=4096, SCALE=1)
#define Bb 32
#define Pp 256
#define Dd 64
#define Tt 4096

typedef unsigned short ushort_t;
typedef __attribute__((ext_vector_type(8))) short bf16x8;   // 8 bf16 = 4 VGPRs
typedef __attribute__((ext_vector_type(4))) float f32x4;

#define SEG16_BYTES ((size_t)Bb * 16 * Tt * 4)   // 8,388,608
#define B_BF_BYTES  ((size_t)Tt * Dd * 2)        //   524,288 (each of hi/lo)

// x = hi(bf16,RNE) + lo(bf16): dropped al*bl term ~2^-17 rel; pred err ~5e-4.
__device__ __forceinline__ void split8(const float* __restrict__ x,
                                       bf16x8& hi, bf16x8& lo) {
#pragma unroll
  for (int j = 0; j < 8; ++j) {
    const __hip_bfloat16 hb = __float2bfloat16(x[j]);
    const float hf = __bfloat162float(hb);
    const __hip_bfloat16 lb = __float2bfloat16(x[j] - hf);
    hi[j] = *(const short*)&hb;
    lo[j] = *(const short*)&lb;
  }
}

#define MFMA6(a)                                                     \
  a = __builtin_amdgcn_mfma_f32_16x16x32_bf16(ah0, bh0, a, 0, 0, 0); \
  a = __builtin_amdgcn_mfma_f32_16x16x32_bf16(ah1, bh1, a, 0, 0, 0); \
  a = __builtin_amdgcn_mfma_f32_16x16x32_bf16(ah0, bl0, a, 0, 0, 0); \
  a = __builtin_amdgcn_mfma_f32_16x16x32_bf16(al0, bh0, a, 0, 0, 0); \
  a = __builtin_amdgcn_mfma_f32_16x16x32_bf16(ah1, bl1, a, 0, 0, 0); \
  a = __builtin_amdgcn_mfma_f32_16x16x32_bf16(al1, bh1, a, 0, 0, 0);

// =============== Phase 0: split-bf16 conversion of W (once) =================
// R10 post-mortem: in-kernel B-splits were ~5x the MFMA issue cycles and were
// redone redundantly by every block. Do it once: 262144 elements, 1 MB out.
__global__ __launch_bounds__(256) void k_convB(const float* __restrict__ Wt,
                                               ushort_t* __restrict__ Bh,
                                               ushort_t* __restrict__ Bl) {
  const int i = blockIdx.x * 256 + threadIdx.x;   // exactly Tt*Dd threads
  const float x = Wt[i];
  const __hip_bfloat16 h = __float2bfloat16(x);
  const float hf = __bfloat162float(h);
  const __hip_bfloat16 l = __float2bfloat16(x - hf);
  Bh[i] = *(const ushort_t*)&h;
  Bl[i] = *(const ushort_t*)&l;
}

// ===================== Phase 1: segment score sums ==========================
// NO pred materialization (R8-R10: the 147MB pred write walls at ~2.2TB/s ->
// 70-90us no matter the store pattern). This kernel computes pred tiles in
// registers (split-bf16 MFMA, R9-proven layout: A m=l16, B n=l16 from W^T
// rows, C/D col=l16 row=quad*4+reg) and emits ONLY the 16-p segment score
// sums seg[b][16][t] (8 MB). Grid (b,sg,tchunk)=2048 blocks; wave owns 256 t.
__global__ __launch_bounds__(256, 2) void k_seg(const float* __restrict__ A,
                                                const ushort_t* __restrict__ Bh,
                                                const ushort_t* __restrict__ Bl,
                                                const float* __restrict__ targets,
                                                float* __restrict__ seg) {
  const int tid = threadIdx.x, wid = tid >> 6, lane = tid & 63;
  const int quad = lane >> 4, l16 = lane & 15;
  const int bs = blockIdx.x >> 2;        // b*16 + sg
  const int tc = blockIdx.x & 3;
  const int b  = bs >> 4, sg = bs & 15;
  const int p0 = sg * 16;

  bf16x8 ah0, al0, ah1, al1;
  {
    const float* ar = A + (size_t)(b * Pp + p0 + l16) * Dd;
    float a0[8], a1[8];
    *(float4*)&a0[0] = *(const float4*)(ar + quad * 8);
    *(float4*)&a0[4] = *(const float4*)(ar + quad * 8 + 4);
    *(float4*)&a1[0] = *(const float4*)(ar + 32 + quad * 8);
    *(float4*)&a1[4] = *(const float4*)(ar + 32 + quad * 8 + 4);
    split8(a0, ah0, al0);
    split8(a1, ah1, al1);
  }
  const float4 tq = *(const float4*)(targets + b * Pp + p0 + quad * 4);
  const int tbase = tc * 1024 + wid * 256;
  float* segrow = seg + (size_t)bs * Tt;

#pragma unroll
  for (int nt = 0; nt < 16; ++nt) {
    const int t = tbase + nt * 16 + l16;
    const size_t boff = (size_t)t * Dd + quad * 8;
    const bf16x8 bh0 = *(const bf16x8*)(Bh + boff);
    const bf16x8 bh1 = *(const bf16x8*)(Bh + boff + 32);
    const bf16x8 bl0 = *(const bf16x8*)(Bl + boff);
    const bf16x8 bl1 = *(const bf16x8*)(Bl + boff + 32);
    f32x4 a = (f32x4)0.f;
    MFMA6(a)
    float cs = 0.f;
    { const float e = tq.x - a[0]; cs = fmaf(-0.5f * e, e, cs); }
    { const float e = tq.y - a[1]; cs = fmaf(-0.5f * e, e, cs); }
    { const float e = tq.z - a[2]; cs = fmaf(-0.5f * e, e, cs); }
    { const float e = tq.w - a[3]; cs = fmaf(-0.5f * e, e, cs); }
    const float s1  = cs + __shfl_xor(cs, 16, 64);
    const float tot = s1 + __shfl_xor(s1, 32, 64);
    if (quad == 0) segrow[t] = tot;     // 16 lanes -> 64B contiguous
  }
}

// ============== Phase 2: exclusive scan of the 16 segment sums ==============
__global__ __launch_bounds__(256) void k_segscan(float* __restrict__ seg) {
  const int gt = blockIdx.x * 256 + threadIdx.x;   // Bb*Tt threads
  const int b  = gt >> 12;
  const int t  = gt & (Tt - 1);
  float* col = seg + (size_t)b * 16 * Tt + t;
  float run = 0.f;
#pragma unroll
  for (int s = 0; s < 16; ++s) {
    const float v = col[(size_t)s * Tt];
    col[(size_t)s * Tt] = run;
    run += v;
  }
}

// ================== Phase 3: fused recompute + prefix softmax ===============
// Block owns (b, 16-p segment, ALL 4096 t); 4 chunks x 16 nt per wave.
// Scores recomputed bitwise-identically to k_seg (same frags, same MFMA
// order). Per t-column (fixed l16): 16 p-rows live in the 4 quads x 4 regs of
// ONE wave -> exclusive prefix = 3 shfl_xor (quad prefix) + in-register reg
// prefix. Per-lane online softmax (m,s,v)[4] over its 64 t-cols; final merge:
// xor 1/2/4/8 within quad, LDS across waves. Writes only out (32 KB total).
// NaN-safety: running max is exact at convergence -> argmax elem has e=1 ->
// S>=1 (R3 lesson); merges use the factored exp(m-M) form throughout.
__global__ __launch_bounds__(256, 2) void k_fused(const float* __restrict__ A,
                                                  const ushort_t* __restrict__ Bh,
                                                  const ushort_t* __restrict__ Bl,
                                                  const float* __restrict__ targets,
                                                  const float* __restrict__ segbase,
                                                  float* __restrict__ out) {
  __shared__ float redM[4][16], redS[4][16], redV[4][16];
  const int tid = threadIdx.x, wid = tid >> 6, lane = tid & 63;
  const int quad = lane >> 4, l16 = lane & 15;
  const int bs = blockIdx.x;             // b*16 + sg
  const int b  = bs >> 4, sg = bs & 15;
  const int p0 = sg * 16;

  bf16x8 ah0, al0, ah1, al1;
  {
    const float* ar = A + (size_t)(b * Pp + p0 + l16) * Dd;
    float a0[8], a1[8];
    *(float4*)&a0[0] = *(const float4*)(ar + quad * 8);
    *(float4*)&a0[4] = *(const float4*)(ar + quad * 8 + 4);
    *(float4*)&a1[0] = *(const float4*)(ar + 32 + quad * 8);
    *(float4*)&a1[4] = *(const float4*)(ar + 32 + quad * 8 + 4);
    split8(a0, ah0, al0);
    split8(a1, ah1, al1);
  }
  const float4 tq = *(const float4*)(targets + b * Pp + p0 + quad * 4);
  const float* segrow = segbase + (size_t)bs * Tt;

  float mm[4], ss[4], vv[4];
#pragma unroll
  for (int r = 0; r < 4; ++r) { mm[r] = -INFINITY; ss[r] = 0.f; vv[r] = 0.f; }

#pragma unroll 1
  for (int chunk = 0; chunk < 4; ++chunk) {
    const int tbase = chunk * 1024 + wid * 256;
#pragma unroll
    for (int nt = 0; nt < 16; ++nt) {
      const int t = tbase + nt * 16 + l16;
      const size_t boff = (size_t)t * Dd + quad * 8;
      const bf16x8 bh0 = *(const bf16x8*)(Bh + boff);
      const bf16x8 bh1 = *(const bf16x8*)(Bh + boff + 32);
      const bf16x8 bl0 = *(const bf16x8*)(Bl + boff);
      const bf16x8 bl1 = *(const bf16x8*)(Bl + boff + 32);
      f32x4 a = (f32x4)0.f;
      MFMA6(a)

      float sc[4];
      { const float e = tq.x - a[0]; sc[0] = -0.5f * e * e; }
      { const float e = tq.y - a[1]; sc[1] = -0.5f * e * e; }
      { const float e = tq.z - a[2]; sc[2] = -0.5f * e * e; }
      { const float e = tq.w - a[3]; sc[3] = -0.5f * e * e; }

      // quad-exclusive prefix of per-column sums (3 shuffles)
      const float colsum = (sc[0] + sc[1]) + (sc[2] + sc[3]);
      const float x1 = __shfl_xor(colsum, 16, 64);        // quad^1
      const float x2 = __shfl_xor(colsum, 32, 64);        // quad^2
      const float x3 = __shfl_xor(x1, 32, 64);            // quad^3
      const float pre = (quad == 0) ? 0.f
                      : (quad == 1) ? x1
                      : (quad == 2) ? (x2 + x3)
                                    : (x1 + x2 + x3);
      const float base = segrow[t] + pre;                 // exclusive global prefix
      float cc[4];
      cc[0] = base;
      cc[1] = base + sc[0];
      cc[2] = cc[1] + sc[1];
      cc[3] = cc[2] + sc[2];

      // online softmax update for this lane's 4 p at column t
#pragma unroll
      for (int r = 0; r < 4; ++r) {
        const float mn = fmaxf(mm[r], cc[r]);
        const float fo = __expf(mm[r] - mn);   // <=1 (0 on first hit)
        const float e  = __expf(cc[r] - mn);   // <=1
        ss[r] = fmaf(ss[r], fo, e);
        vv[r] = fmaf(vv[r], fo, e * a[r]);
        mm[r] = mn;
      }
    }
  }

  // reduce over the 16 l16 lanes (within quad): xor 1,2,4,8
#pragma unroll
  for (int off = 1; off < 16; off <<= 1) {
#pragma unroll
    for (int r = 0; r < 4; ++r) {
      const float mo = __shfl_xor(mm[r], off, 64);
      const float so = __shfl_xor(ss[r], off, 64);
      const float vo = __shfl_xor(vv[r], off, 64);
      const float mn = fmaxf(mm[r], mo);
      const float f0 = __expf(mm[r] - mn), f1 = __expf(mo - mn);
      ss[r] = ss[r] * f0 + so * f1;
      vv[r] = vv[r] * f0 + vo * f1;
      mm[r] = mn;
    }
  }
  if (l16 == 0) {
#pragma unroll
    for (int r = 0; r < 4; ++r) {
      redM[wid][quad * 4 + r] = mm[r];
      redS[wid][quad * 4 + r] = ss[r];
      redV[wid][quad * 4 + r] = vv[r];
    }
  }
  __syncthreads();
  if (tid < 16) {       // p_local = tid
    float M = -INFINITY, S = 0.f, V = 0.f;
#pragma unroll
    for (int w = 0; w < 4; ++w) {
      const float mo = redM[w][tid], so = redS[w][tid], vo = redV[w][tid];
      const float mn = fmaxf(M, mo);
      const float f0 = __expf(M - mn), f1 = __expf(mo - mn);
      S = S * f0 + so * f1;
      V = V * f0 + vo * f1;
      M = mn;
    }
    out[b * Pp + p0 + tid] = V / S;
  }
}

// ============== Fallback (tiny ws): fused R1 structure + merge ==============
__global__ __launch_bounds__(256) void k_scan_fused(const float* __restrict__ data,
                                                    const float* __restrict__ targets,
                                                    const float* __restrict__ task_pool,
                                                    float4* __restrict__ ws) {
  const int b     = blockIdx.x >> 4;
  const int wid   = threadIdx.x >> 6;
  const int lane  = threadIdx.x & 63;
  const int chunk = ((blockIdx.x & 15) << 2) | wid;
  const int t     = (chunk << 6) | lane;
  float w[Dd];
#pragma unroll
  for (int d = 0; d < Dd; d += 4) {
    const float4 r = *(const float4*)(task_pool + (size_t)t * Dd + d);
    w[d] = r.x; w[d + 1] = r.y; w[d + 2] = r.z; w[d + 3] = r.w;
  }
  const float* drow = data + (size_t)b * (Pp * Dd);
  const float* tgt  = targets + b * Pp;
  float4* wsb       = ws + (size_t)b * (Pp * 64);
  float c = 0.f;
  for (int p = 0; p < Pp; ++p) {
    float a0 = 0.f, a1 = 0.f, a2 = 0.f, a3 = 0.f;
    const float* r = drow + p * Dd;
#pragma unroll
    for (int d = 0; d < Dd; d += 4) {
      a0 = fmaf(r[d], w[d], a0);         a1 = fmaf(r[d + 1], w[d + 1], a1);
      a2 = fmaf(r[d + 2], w[d + 2], a2); a3 = fmaf(r[d + 3], w[d + 3], a3);
    }
    const float pred = (a0 + a1) + (a2 + a3);
    float m = c;
#pragma unroll
    for (int off = 32; off; off >>= 1) m = fmaxf(m, __shfl_xor(m, off, 64));
    const float e = __expf(c - m);
    float s = e, v = e * pred;
#pragma unroll
    for (int off = 32; off; off >>= 1) {
      s += __shfl_xor(s, off, 64);
      v += __shfl_xor(v, off, 64);
    }
    if (lane == 0) wsb[p * 64 + chunk] = make_float4(m, s, v, 0.f);
    const float err = tgt[p] - pred;
    c = fmaf(-0.5f * err, err, c);
  }
}

__global__ __launch_bounds__(256) void k_merge(const float4* __restrict__ ws,
                                               float* __restrict__ out) {
  const int gt   = blockIdx.x * 256 + threadIdx.x;
  const int bp   = gt >> 6;
  const int lane = gt & 63;
  const float4 o = ws[(size_t)bp * 64 + lane];
  const float m = o.x, s = o.y, v = o.z;
  float M = m;
#pragma unroll
  for (int off = 32; off; off >>= 1) M = fmaxf(M, __shfl_xor(M, off, 64));
  const float f = __expf(m - M);
  float S = f * s, V = f * v;
#pragma unroll
  for (int off = 32; off; off >>= 1) {
    S += __shfl_xor(S, off, 64);
    V += __shfl_xor(V, off, 64);
  }
  if (lane == 0) out[bp] = V / S;
}

extern "C" void kernel_launch(void* const* d_in, const int* in_sizes, int n_in,
                              void* d_out, int out_size, void* d_ws, size_t ws_size,
                              hipStream_t stream) {
  const float* data      = (const float*)d_in[0];
  const float* targets   = (const float*)d_in[1];
  const float* task_pool = (const float*)d_in[2];
  float* out = (float*)d_out;

  if (ws_size >= SEG16_BYTES + 2 * B_BF_BYTES) {
    float*    seg = (float*)d_ws;
    ushort_t* Bh  = (ushort_t*)((char*)d_ws + SEG16_BYTES);
    ushort_t* Bl  = (ushort_t*)((char*)d_ws + SEG16_BYTES + B_BF_BYTES);
    k_convB  <<<dim3(Tt * Dd / 256), dim3(256), 0, stream>>>(task_pool, Bh, Bl);
    k_seg    <<<dim3(Bb * 16 * 4), dim3(256), 0, stream>>>(data, Bh, Bl, targets, seg);
    k_segscan<<<dim3(Bb * Tt / 256), dim3(256), 0, stream>>>(seg);
    k_fused  <<<dim3(Bb * 16), dim3(256), 0, stream>>>(data, Bh, Bl, targets, seg, out);
  } else {
    float4* triples = (float4*)d_ws;   // 8.4 MB
    k_scan_fused<<<dim3(512), dim3(256), 0, stream>>>(data, targets, task_pool, triples);
    k_merge<<<dim3((Bb * Pp * 64) / 256), dim3(256), 0, stream>>>(triples, out);
  }
}

// Round 12
// 104.641 us; speedup vs baseline: 1.8498x; 1.8498x over previous
//
#include <hip/hip_runtime.h>
#include <hip/hip_bf16.h>
#include <math.h>

// Problem constants (reference: B=32, P=256, D=64, T=4096, SCALE=1)
#define Bb 32
#define Pp 256
#define Dd 64
#define Tt 4096

typedef unsigned short ushort_t;
typedef __attribute__((ext_vector_type(8))) short bf16x8;   // 8 bf16 = 4 VGPRs
typedef __attribute__((ext_vector_type(4))) float f32x4;

#define TRIP_BYTES ((size_t)Bb * Pp * 64 * 16)   // 8,388,608
#define A_BF_BYTES ((size_t)Bb * Pp * Dd * 2)    // 1,048,576 (each of hi/lo)
#define B_BF_BYTES ((size_t)Tt * Dd * 2)         //   524,288 (each of hi/lo)
#define WS_NEED    (TRIP_BYTES + 2 * A_BF_BYTES + 2 * B_BF_BYTES)

#define MFMA6(a)                                                     \
  a = __builtin_amdgcn_mfma_f32_16x16x32_bf16(ah0, bh0, a, 0, 0, 0); \
  a = __builtin_amdgcn_mfma_f32_16x16x32_bf16(ah1, bh1, a, 0, 0, 0); \
  a = __builtin_amdgcn_mfma_f32_16x16x32_bf16(ah0, bl0, a, 0, 0, 0); \
  a = __builtin_amdgcn_mfma_f32_16x16x32_bf16(al0, bh0, a, 0, 0, 0); \
  a = __builtin_amdgcn_mfma_f32_16x16x32_bf16(ah1, bl1, a, 0, 0, 0); \
  a = __builtin_amdgcn_mfma_f32_16x16x32_bf16(al1, bh1, a, 0, 0, 0);

// =============== Phase 0: split-bf16 conversion of A and B ==================
// x = hi(bf16,RNE) + lo(bf16); dropped al*bl term ~2^-17 rel; pred err ~5e-4.
__global__ __launch_bounds__(256) void k_conv(const float* __restrict__ data,
                                              const float* __restrict__ Wt,
                                              ushort_t* __restrict__ Ah, ushort_t* __restrict__ Al,
                                              ushort_t* __restrict__ Bh, ushort_t* __restrict__ Bl) {
  const int i  = blockIdx.x * 256 + threadIdx.x;
  const int NA = Bb * Pp * Dd;    // 524288
  const float x = (i < NA) ? data[i] : Wt[i - NA];
  const __hip_bfloat16 h = __float2bfloat16(x);
  const float hf = __bfloat162float(h);
  const __hip_bfloat16 l = __float2bfloat16(x - hf);
  if (i < NA) { Ah[i] = *(const ushort_t*)&h; Al[i] = *(const ushort_t*)&l; }
  else        { const int j = i - NA;
                Bh[j] = *(const ushort_t*)&h; Bl[j] = *(const ushort_t*)&l; }
}

// ==================== Phase 1: one-pass fused prefix-softmax ================
// R11 post-mortem: partitioning by (b,sg) forced every block to re-read ALL of
// B (1 GB L2 total) and required seg+segscan pre-passes. R12: block owns
// (b, 256-t strip) and iterates sg=0..15 SERIALLY, computing the prefix
// in-kernel (seg/segscan kernels deleted; B-strip staged ONCE in LDS, 74 KB).
// Per sg: A-frags (4 coalesced dwordx4, wave-shared -> L1), 4 nt tiles x
// 6 split-bf16 MFMAs (R9-proven layout: A m=l16, B n=l16, C/D col=l16
// row=quad*4+reg), scores, quad-exclusive prefix (3 shuffles, R11-proven),
// loop-carried per-column prefix R[nt], then a BATCH softmax over the 16
// in-register cc values (exact per-r max over 4 nt), one 4-round l16
// butterfly (fmax rounds -> single rescale (4 exp) -> plain-sum rounds), and
// 4 float4 triple stores. Cross-strip merge: k_merge (R6-proven, 64-wide).
// NaN-safety (R3): per-wave M is the exact max of that wave's cc -> the
// argmax term contributes exp(0)=1 -> S>=1; factored exp(m-M) merges exact.
__global__ __launch_bounds__(256, 2) void k_main(const ushort_t* __restrict__ Ah,
                                                 const ushort_t* __restrict__ Al,
                                                 const ushort_t* __restrict__ Bh,
                                                 const ushort_t* __restrict__ Bl,
                                                 const float* __restrict__ targets,
                                                 float4* __restrict__ triples) {
  __shared__ short Bhs[256 * 72];   // padded rows: 72 shorts = 144 B (16B-aligned)
  __shared__ short Bls[256 * 72];
  const int tid  = threadIdx.x;
  const int wid  = tid >> 6;
  const int lane = tid & 63;
  const int quad = lane >> 4;
  const int l16  = lane & 15;
  const int b     = blockIdx.x >> 4;
  const int strip = blockIdx.x & 15;
  const int t0    = strip * 256;

  // ---- stage B-strip into LDS (once): 2048 float4 per array, coalesced
  {
    const float4* sh = (const float4*)(Bh + (size_t)t0 * Dd);
    const float4* sl = (const float4*)(Bl + (size_t)t0 * Dd);
#pragma unroll
    for (int j = 0; j < 8; ++j) {
      const int idx = tid + j * 256;            // block-local float4 index
      const int tl  = idx >> 3;                 // local t row
      const int col = (idx & 7) * 8;            // short col within row
      *(float4*)&Bhs[tl * 72 + col] = sh[idx];
      *(float4*)&Bls[tl * 72 + col] = sl[idx];
    }
  }
  __syncthreads();

  const ushort_t* arow_base = Ah + (size_t)b * Pp * Dd;
  const ushort_t* alow_base = Al + (size_t)b * Pp * Dd;
  float4* __restrict__ trb  = triples + (size_t)b * Pp * 64;
  const int wstrip = strip * 4 + wid;           // 0..63 (this wave's t-subset id)

  float R[4];                                   // per-column running prefix
#pragma unroll
  for (int nt = 0; nt < 4; ++nt) R[nt] = 0.f;

#pragma unroll 1
  for (int sg = 0; sg < 16; ++sg) {
    const int p0 = sg * 16;
    // A fragments for rows p0..p0+15 (coalesced 2KB per wave, same for all waves)
    const size_t aoff = (size_t)(p0 + l16) * Dd + quad * 8;
    const bf16x8 ah0 = *(const bf16x8*)(arow_base + aoff);
    const bf16x8 ah1 = *(const bf16x8*)(arow_base + aoff + 32);
    const bf16x8 al0 = *(const bf16x8*)(alow_base + aoff);
    const bf16x8 al1 = *(const bf16x8*)(alow_base + aoff + 32);
    const float4 tq  = *(const float4*)(targets + b * Pp + p0 + quad * 4);

    float cc[4][4], av[4][4];
#pragma unroll
    for (int nt = 0; nt < 4; ++nt) {
      const int tl = wid * 64 + nt * 16 + l16;  // local t row in LDS
      const int bo = tl * 72 + quad * 8;
      const bf16x8 bh0 = *(const bf16x8*)&Bhs[bo];
      const bf16x8 bh1 = *(const bf16x8*)&Bhs[bo + 32];
      const bf16x8 bl0 = *(const bf16x8*)&Bls[bo];
      const bf16x8 bl1 = *(const bf16x8*)&Bls[bo + 32];
      f32x4 a = (f32x4)0.f;
      MFMA6(a)

      float sc[4];
      { const float e = tq.x - a[0]; sc[0] = -0.5f * e * e; }
      { const float e = tq.y - a[1]; sc[1] = -0.5f * e * e; }
      { const float e = tq.z - a[2]; sc[2] = -0.5f * e * e; }
      { const float e = tq.w - a[3]; sc[3] = -0.5f * e * e; }

      // quad-exclusive prefix of column sums (R11-proven)
      const float colsum = (sc[0] + sc[1]) + (sc[2] + sc[3]);
      const float x1 = __shfl_xor(colsum, 16, 64);
      const float x2 = __shfl_xor(colsum, 32, 64);
      const float x3 = __shfl_xor(x1, 32, 64);
      const float pre = (quad == 0) ? 0.f
                      : (quad == 1) ? x1
                      : (quad == 2) ? (x2 + x3)
                                    : (x1 + x2 + x3);
      const float base = R[nt] + pre;
      cc[nt][0] = base;
      cc[nt][1] = base + sc[0];
      cc[nt][2] = cc[nt][1] + sc[1];
      cc[nt][3] = cc[nt][2] + sc[2];
#pragma unroll
      for (int r = 0; r < 4; ++r) av[nt][r] = a[r];

      R[nt] += ((colsum + x1) + (x2 + x3));     // inclusive through this sg
    }

    // batch softmax over this lane's 4 columns, per p-row r
    float mm[4], ss[4], vv[4];
#pragma unroll
    for (int r = 0; r < 4; ++r) {
      const float m01 = fmaxf(cc[0][r], cc[1][r]);
      const float m23 = fmaxf(cc[2][r], cc[3][r]);
      mm[r] = fmaxf(m01, m23);
      float s = 0.f, v = 0.f;
#pragma unroll
      for (int nt = 0; nt < 4; ++nt) {
        const float e = __expf(cc[nt][r] - mm[r]);
        s += e;
        v = fmaf(e, av[nt][r], v);
      }
      ss[r] = s; vv[r] = v;
    }

    // l16 butterfly: exact max rounds, single rescale, plain-sum rounds
    float M[4];
#pragma unroll
    for (int r = 0; r < 4; ++r) M[r] = mm[r];
#pragma unroll
    for (int off = 1; off < 16; off <<= 1)
#pragma unroll
      for (int r = 0; r < 4; ++r) M[r] = fmaxf(M[r], __shfl_xor(M[r], off, 64));
#pragma unroll
    for (int r = 0; r < 4; ++r) {
      const float f = __expf(mm[r] - M[r]);     // ==1 at the argmax lane
      ss[r] *= f; vv[r] *= f;
    }
#pragma unroll
    for (int off = 1; off < 16; off <<= 1)
#pragma unroll
      for (int r = 0; r < 4; ++r) {
        ss[r] += __shfl_xor(ss[r], off, 64);
        vv[r] += __shfl_xor(vv[r], off, 64);
      }

    if (l16 == 0) {
#pragma unroll
      for (int r = 0; r < 4; ++r) {
        const int p = p0 + quad * 4 + r;
        trb[p * 64 + wstrip] = make_float4(M[r], ss[r], vv[r], 0.f);
      }
    }
  }
}

// ==================== Phase 2: cross-strip merge (R6-proven) ================
__global__ __launch_bounds__(256) void k_merge(const float4* __restrict__ ws,
                                               float* __restrict__ out) {
  const int gt   = blockIdx.x * 256 + threadIdx.x;
  const int bp   = gt >> 6;
  const int lane = gt & 63;
  const float4 o = ws[(size_t)bp * 64 + lane];
  const float m = o.x, s = o.y, v = o.z;
  float M = m;
#pragma unroll
  for (int off = 32; off; off >>= 1) M = fmaxf(M, __shfl_xor(M, off, 64));
  const float f = __expf(m - M);
  float S = f * s, V = f * v;
#pragma unroll
  for (int off = 32; off; off >>= 1) {
    S += __shfl_xor(S, off, 64);
    V += __shfl_xor(V, off, 64);
  }
  if (lane == 0) out[bp] = V / S;
}

// ============== Fallback (tiny ws): fused R1 structure + merge ==============
__global__ __launch_bounds__(256) void k_scan_fused(const float* __restrict__ data,
                                                    const float* __restrict__ targets,
                                                    const float* __restrict__ task_pool,
                                                    float4* __restrict__ ws) {
  const int b     = blockIdx.x >> 4;
  const int wid   = threadIdx.x >> 6;
  const int lane  = threadIdx.x & 63;
  const int chunk = ((blockIdx.x & 15) << 2) | wid;
  const int t     = (chunk << 6) | lane;
  float w[Dd];
#pragma unroll
  for (int d = 0; d < Dd; d += 4) {
    const float4 r = *(const float4*)(task_pool + (size_t)t * Dd + d);
    w[d] = r.x; w[d + 1] = r.y; w[d + 2] = r.z; w[d + 3] = r.w;
  }
  const float* drow = data + (size_t)b * (Pp * Dd);
  const float* tgt  = targets + b * Pp;
  float4* wsb       = ws + (size_t)b * (Pp * 64);
  float c = 0.f;
  for (int p = 0; p < Pp; ++p) {
    float a0 = 0.f, a1 = 0.f, a2 = 0.f, a3 = 0.f;
    const float* r = drow + p * Dd;
#pragma unroll
    for (int d = 0; d < Dd; d += 4) {
      a0 = fmaf(r[d], w[d], a0);         a1 = fmaf(r[d + 1], w[d + 1], a1);
      a2 = fmaf(r[d + 2], w[d + 2], a2); a3 = fmaf(r[d + 3], w[d + 3], a3);
    }
    const float pred = (a0 + a1) + (a2 + a3);
    float m = c;
#pragma unroll
    for (int off = 32; off; off >>= 1) m = fmaxf(m, __shfl_xor(m, off, 64));
    const float e = __expf(c - m);
    float s = e, v = e * pred;
#pragma unroll
    for (int off = 32; off; off >>= 1) {
      s += __shfl_xor(s, off, 64);
      v += __shfl_xor(v, off, 64);
    }
    if (lane == 0) wsb[p * 64 + chunk] = make_float4(m, s, v, 0.f);
    const float err = tgt[p] - pred;
    c = fmaf(-0.5f * err, err, c);
  }
}

extern "C" void kernel_launch(void* const* d_in, const int* in_sizes, int n_in,
                              void* d_out, int out_size, void* d_ws, size_t ws_size,
                              hipStream_t stream) {
  const float* data      = (const float*)d_in[0];
  const float* targets   = (const float*)d_in[1];
  const float* task_pool = (const float*)d_in[2];
  float* out = (float*)d_out;

  if (ws_size >= WS_NEED) {
    float4*   trips = (float4*)d_ws;
    char*     cb    = (char*)d_ws + TRIP_BYTES;
    ushort_t* Ah    = (ushort_t*)cb;
    ushort_t* Al    = (ushort_t*)(cb + A_BF_BYTES);
    ushort_t* Bh    = (ushort_t*)(cb + 2 * A_BF_BYTES);
    ushort_t* Bl    = (ushort_t*)(cb + 2 * A_BF_BYTES + B_BF_BYTES);
    k_conv <<<dim3((Bb * Pp * Dd + Tt * Dd) / 256), dim3(256), 0, stream>>>(
        data, task_pool, Ah, Al, Bh, Bl);
    k_main <<<dim3(Bb * 16), dim3(256), 0, stream>>>(Ah, Al, Bh, Bl, targets, trips);
    k_merge<<<dim3((Bb * Pp * 64) / 256), dim3(256), 0, stream>>>(trips, out);
  } else {
    float4* triples = (float4*)d_ws;   // 8.4 MB
    k_scan_fused<<<dim3(512), dim3(256), 0, stream>>>(data, targets, task_pool, triples);
    k_merge<<<dim3((Bb * Pp * 64) / 256), dim3(256), 0, stream>>>(triples, out);
  }
}